// Round 2
// baseline (3723.100 us; speedup 1.0000x reference)
//
#include <hip/hip_runtime.h>
#include <hip/hip_bf16.h>
#include <stdint.h>

#define B_ 128
#define S_ 256
#define H_ 256

typedef __attribute__((ext_vector_type(8))) short short8;
typedef __attribute__((ext_vector_type(4))) float f32x4;

__device__ __forceinline__ short f2bf_s(float x){
    union { __hip_bfloat16 b; short s; } u; u.b = __float2bfloat16(x); return u.s;
}
__device__ __forceinline__ float bf2f_s(short s){
    union { __hip_bfloat16 b; short s2; } u; u.s2 = s; return __bfloat162float(u.b);
}
__device__ __forceinline__ void load_lds16(const void* g, void* l){
    __builtin_amdgcn_global_load_lds(
        (const __attribute__((address_space(1))) void*)g,
        (__attribute__((address_space(3))) void*)l, 16, 0, 0);
}
__device__ __forceinline__ float sigmoidf_(float x){
    return 1.0f / (1.0f + __expf(-x));
}

// ---------- conversion kernels ----------

// x [32768][1024] f32 -> xin[:, 0:1024) bf16 (xin row stride 2048)
__global__ void k_cvt_x(const float* __restrict__ x, short* __restrict__ xin){
    int q = blockIdx.x * blockDim.x + threadIdx.x;   // quad index, total 8388608
    if (q >= 8388608) return;
    const float4 v = ((const float4*)x)[q];
    int r = q >> 8;            // row (256 quads per row)
    int c4 = (q & 255) << 2;   // col
    short4 o;
    o.x = f2bf_s(v.x); o.y = f2bf_s(v.y); o.z = f2bf_s(v.z); o.w = f2bf_s(v.w);
    *(short4*)(xin + (int64_t)r * 2048 + c4) = o;
}

// stages [32768][67] f32 -> stagesP [32768][96] bf16 (zero pad)
__global__ void k_cvt_stages(const float* __restrict__ st, short* __restrict__ sp){
    int i = blockIdx.x * blockDim.x + threadIdx.x;   // total 32768*96
    if (i >= 32768 * 96) return;
    int r = i / 96, k = i - r * 96;
    sp[i] = (k < 67) ? f2bf_s(st[(int64_t)r * 67 + k]) : (short)0;
}

// w [K][N] f32 -> wt [N][Kpad] bf16 (zero pad k>=K)
__global__ void k_transpose(const float* __restrict__ w, short* __restrict__ wt,
                            int K, int N, int Kpad){
    int i = blockIdx.x * blockDim.x + threadIdx.x;   // total N*Kpad
    if (i >= N * Kpad) return;
    int n = i / Kpad, k = i - n * Kpad;
    wt[i] = (k < K) ? f2bf_s(w[(int64_t)k * N + n]) : (short)0;
}

// ---------- bf16 MFMA GEMM: C[M,N] = A[M,K] @ BT[N,K]^T + bias ----------
// 128x128 tile, BK=32, 256 threads, global_load_lds width-16 staging (m97 structure)
// flags: 1=relu, 2=store bf16 to Cb, 4=permuted f32 store (u layout [s][b][1024])
__global__ __launch_bounds__(256) void k_gemm(
    const short* __restrict__ A, int lda,
    const short* __restrict__ BT, int ldb,
    const float* __restrict__ bias,
    int K, int flags,
    float* __restrict__ Cf, short* __restrict__ Cb, int ldc)
{
    __shared__ __align__(16) short At[128 * 32];
    __shared__ __align__(16) short Bt[128 * 32];
    const int tid = threadIdx.x;
    const int lane = tid & 63, w = tid >> 6;
    const int q = lane >> 4, m = lane & 15;
    const int wr = w >> 1, wc = w & 1;
    const int bm = blockIdx.y, bn = blockIdx.x;

    const short* Ablk = A + (int64_t)bm * 128 * lda;
    const short* Bblk = BT + (int64_t)bn * 128 * ldb;

    f32x4 acc[4][4] = {};

    for (int k0 = 0; k0 < K; k0 += 32){
#pragma unroll
        for (int call = 0; call < 2; ++call){
            int chunk = (call * 4 + w) * 64 + lane;
            int row = chunk >> 2, co = (chunk & 3) * 8;
            load_lds16(Ablk + (int64_t)row * lda + k0 + co, At + (call * 4 + w) * 512);
            load_lds16(Bblk + (int64_t)row * ldb + k0 + co, Bt + (call * 4 + w) * 512);
        }
        __syncthreads();
        short8 af[4], bfr[4];
#pragma unroll
        for (int mt = 0; mt < 4; ++mt)
            af[mt] = *(const short8*)(At + (wr * 64 + mt * 16 + m) * 32 + q * 8);
#pragma unroll
        for (int nt = 0; nt < 4; ++nt)
            bfr[nt] = *(const short8*)(Bt + (wc * 64 + nt * 16 + m) * 32 + q * 8);
#pragma unroll
        for (int mt = 0; mt < 4; ++mt)
#pragma unroll
            for (int nt = 0; nt < 4; ++nt)
                acc[mt][nt] = __builtin_amdgcn_mfma_f32_16x16x32_bf16(
                    af[mt], bfr[nt], acc[mt][nt], 0, 0, 0);
        __syncthreads();
    }

#pragma unroll
    for (int mt = 0; mt < 4; ++mt){
#pragma unroll
        for (int nt = 0; nt < 4; ++nt){
            int col = bn * 128 + wc * 64 + nt * 16 + m;
            float bv = bias[col];
#pragma unroll
            for (int rg = 0; rg < 4; ++rg){
                int row = bm * 128 + wr * 64 + mt * 16 + q * 4 + rg;
                float v = acc[mt][nt][rg] + bv;
                if (flags & 1) v = fmaxf(v, 0.0f);
                if (flags & 2){
                    Cb[(int64_t)row * ldc + col] = f2bf_s(v);
                } else if (flags & 4){
                    int s = row & 255, b = row >> 8;
                    Cf[((int64_t)s * 128 + b) * 1024 + col] = v;
                } else {
                    Cf[(int64_t)row * ldc + col] = v;
                }
            }
        }
    }
}

// ---------- TLSTM scan ----------
// 256 WGs = 8 row-groups (16 batch rows each) x 32 col-groups (8 cell cols each).
// Weights resident in LDS as bf16 hi/lo B-fragments (bf16x3 ~ f32 precision).
// h/c exchanged as packed (hi|lo<<16) u32 words; sc1-bypassing atomic loads.
// Sync: per-(row-group,step) monotonic counter. Producer signals with a
// RELEASE fetch_add (emits vmcnt(0)+buffer_wbl2 -> all dirty L2 lines reach
// the LLC before the count bumps). Consumer spins with ACQUIRE loads (emits
// buffer_inv). feat is stored nontemporally so the per-step wbl2 stays cheap.
__global__ __launch_bounds__(256, 2) void k_scan(
    const float* __restrict__ W_all, const float* __restrict__ W_all_b,
    const float* __restrict__ W_d,   const float* __restrict__ W_d_b,
    const float* __restrict__ u,     const float* __restrict__ tsp,
    unsigned* __restrict__ ctr,      // [8][256]
    unsigned* __restrict__ h_pk,     // [2][128][256] packed bf16 hi|lo
    unsigned* __restrict__ c_pk,
    float* __restrict__ feat)        // [B][S][H]
{
    __shared__ __align__(16) short wf_hi[3][8][64][8];
    __shared__ __align__(16) short wf_lo[3][8][64][8];
    __shared__ float Dg[3][16][17];

    const int tid = threadIdx.x;
    const int r = blockIdx.x >> 5, cg = blockIdx.x & 31;
    const int j0 = cg * 8, row0 = r * 16;

    // one-time: load this WG's weight slice into LDS fragments (hi/lo bf16)
    for (int idx = tid; idx < 3 * 8 * 64; idx += 256){
        int t = idx / 512;
        int kk = (idx >> 6) & 7;
        int ln = idx & 63;
        int qq = ln >> 4, nn = ln & 15;
#pragma unroll
        for (int jj = 0; jj < 8; ++jj){
            int k = kk * 32 + qq * 8 + jj;
            float v = 0.0f;
            if (t < 2){
                int ngl = (nn < 8) ? (t * 512 + j0 + nn) : (t * 512 + 256 + j0 + nn - 8);
                v = W_all[(int64_t)k * 1024 + ngl];
            } else if (nn < 8){
                v = W_d[(int64_t)k * 256 + j0 + nn];
            }
            short hi = f2bf_s(v);
            wf_hi[t][kk][ln][jj] = hi;
            wf_lo[t][kk][ln][jj] = f2bf_s(v - bf2f_s(hi));
        }
    }
    __syncthreads();

    const int lane = tid & 63, w = tid >> 6;
    const int q = lane >> 4, al15 = lane & 15;

    for (int s = 0; s < 256; ++s){
        if (s > 0 && tid == 0){
            while (__hip_atomic_load(&ctr[r * 256 + s - 1],
                                     __ATOMIC_ACQUIRE, __HIP_MEMORY_SCOPE_AGENT) < 32u)
                __builtin_amdgcn_s_sleep(1);
        }
        __syncthreads();

        const int pin = (s + 1) & 1;   // state after step s-1

        if (w < 3){
            const unsigned* src = (w < 2 ? h_pk : c_pk) + pin * 32768 + (row0 + al15) * 256;
            f32x4 acc = {0.0f, 0.0f, 0.0f, 0.0f};
#pragma unroll
            for (int kk = 0; kk < 8; ++kk){
                int kb = kk * 32 + q * 8;
                const unsigned long long* p64 = (const unsigned long long*)(src + kb);
                unsigned long long d0 = __hip_atomic_load(p64 + 0, __ATOMIC_RELAXED, __HIP_MEMORY_SCOPE_AGENT);
                unsigned long long d1 = __hip_atomic_load(p64 + 1, __ATOMIC_RELAXED, __HIP_MEMORY_SCOPE_AGENT);
                unsigned long long d2 = __hip_atomic_load(p64 + 2, __ATOMIC_RELAXED, __HIP_MEMORY_SCOPE_AGENT);
                unsigned long long d3 = __hip_atomic_load(p64 + 3, __ATOMIC_RELAXED, __HIP_MEMORY_SCOPE_AGENT);
                unsigned w0 = (unsigned)d0, w1 = (unsigned)(d0 >> 32);
                unsigned w2 = (unsigned)d1, w3 = (unsigned)(d1 >> 32);
                unsigned w4 = (unsigned)d2, w5 = (unsigned)(d2 >> 32);
                unsigned w6 = (unsigned)d3, w7 = (unsigned)(d3 >> 32);
                union { short8 v; unsigned u32[4]; } ah, al;
                ah.u32[0] = __builtin_amdgcn_perm(w1, w0, 0x05040100u);
                ah.u32[1] = __builtin_amdgcn_perm(w3, w2, 0x05040100u);
                ah.u32[2] = __builtin_amdgcn_perm(w5, w4, 0x05040100u);
                ah.u32[3] = __builtin_amdgcn_perm(w7, w6, 0x05040100u);
                al.u32[0] = __builtin_amdgcn_perm(w1, w0, 0x07060302u);
                al.u32[1] = __builtin_amdgcn_perm(w3, w2, 0x07060302u);
                al.u32[2] = __builtin_amdgcn_perm(w5, w4, 0x07060302u);
                al.u32[3] = __builtin_amdgcn_perm(w7, w6, 0x07060302u);
                short8 bh = *(const short8*)&wf_hi[w][kk][lane][0];
                short8 bl = *(const short8*)&wf_lo[w][kk][lane][0];
                acc = __builtin_amdgcn_mfma_f32_16x16x32_bf16(ah.v, bh, acc, 0, 0, 0);
                acc = __builtin_amdgcn_mfma_f32_16x16x32_bf16(ah.v, bl, acc, 0, 0, 0);
                acc = __builtin_amdgcn_mfma_f32_16x16x32_bf16(al.v, bh, acc, 0, 0, 0);
            }
#pragma unroll
            for (int rg = 0; rg < 4; ++rg)
                Dg[w][q * 4 + rg][al15] = acc[rg];
        }
        __syncthreads();

        if (tid < 128){
            int b = tid >> 3, jl = tid & 7;
            int gb = row0 + b, gj = j0 + jl;
            const float* urow = u + ((int64_t)s * 128 + gb) * 1024;
            float fpre = Dg[0][b][jl]     + urow[gj]        + W_all_b[gj];
            float ipre = Dg[0][b][8 + jl] + urow[256 + gj]  + W_all_b[256 + gj];
            float opre = Dg[1][b][jl]     + urow[512 + gj]  + W_all_b[512 + gj];
            float gpre = Dg[1][b][8 + jl] + urow[768 + gj]  + W_all_b[768 + gj];
            float spre = Dg[2][b][jl]     + W_d_b[gj];

            unsigned cw = __hip_atomic_load(&c_pk[pin * 32768 + gb * 256 + gj],
                                            __ATOMIC_RELAXED, __HIP_MEMORY_SCOPE_AGENT);
            float c_old = bf2f_s((short)(cw & 0xffffu)) + bf2f_s((short)(cw >> 16));

            float tt  = tsp[gb * 256 + s];
            float cs1 = tanhf(spre);
            float cadj = (c_old - cs1) + cs1 * tt;
            float fg = sigmoidf_(fpre);
            float ig = sigmoidf_(ipre);
            float og = sigmoidf_(opre);
            float gg = sigmoidf_(gpre);
            float cn = fg * cadj + ig * gg;
            float hn = og * tanhf(cn);

            short chi = f2bf_s(cn);
            unsigned cword = (unsigned)(unsigned short)chi |
                             ((unsigned)(unsigned short)f2bf_s(cn - bf2f_s(chi)) << 16);
            short hhi = f2bf_s(hn);
            unsigned hword = (unsigned)(unsigned short)hhi |
                             ((unsigned)(unsigned short)f2bf_s(hn - bf2f_s(hhi)) << 16);
            int pout = s & 1;
            __hip_atomic_store(&c_pk[pout * 32768 + gb * 256 + gj], cword,
                               __ATOMIC_RELAXED, __HIP_MEMORY_SCOPE_AGENT);
            __hip_atomic_store(&h_pk[pout * 32768 + gb * 256 + gj], hword,
                               __ATOMIC_RELAXED, __HIP_MEMORY_SCOPE_AGENT);
            __builtin_nontemporal_store(hn, &feat[((int64_t)gb * 256 + s) * 256 + gj]);
        }
        __syncthreads();   // intra-WG HB edge: all waves' stores precede tid0's release
        if (tid == 0)
            __hip_atomic_fetch_add(&ctr[r * 256 + s], 1u,
                                   __ATOMIC_RELEASE, __HIP_MEMORY_SCOPE_AGENT);
    }
}

// ---------- classifier: out[r] = feat[r,:] . cls_w + cls_b ----------
__global__ __launch_bounds__(256) void k_cls(
    const float* __restrict__ feat, const float* __restrict__ cls_w,
    const float* __restrict__ cls_b, float* __restrict__ out)
{
    int tid = threadIdx.x, lane = tid & 63, w = tid >> 6;
    int row = blockIdx.x * 4 + w;
    float4 v  = ((const float4*)(feat + (int64_t)row * 256))[lane];
    float4 cw = ((const float4*)cls_w)[lane];
    float d = v.x * cw.x + v.y * cw.y + v.z * cw.z + v.w * cw.w;
#pragma unroll
    for (int off = 32; off > 0; off >>= 1)
        d += __shfl_down(d, off, 64);
    if (lane == 0) out[row] = d + cls_b[0];
}

extern "C" void kernel_launch(void* const* d_in, const int* in_sizes, int n_in,
                              void* d_out, int out_size, void* d_ws, size_t ws_size,
                              hipStream_t stream) {
    const float* x      = (const float*)d_in[0];
    const float* stages = (const float*)d_in[1];
    const float* tsp    = (const float*)d_in[2];
    const float* se_w1  = (const float*)d_in[3];
    const float* se_b1  = (const float*)d_in[4];
    const float* se_w2  = (const float*)d_in[5];
    const float* se_b2  = (const float*)d_in[6];
    const float* se_w3  = (const float*)d_in[7];
    const float* se_b3  = (const float*)d_in[8];
    const float* W_all  = (const float*)d_in[9];
    const float* W_allb = (const float*)d_in[10];
    const float* U_w    = (const float*)d_in[11];
    const float* U_b    = (const float*)d_in[12];
    const float* W_d    = (const float*)d_in[13];
    const float* W_d_b  = (const float*)d_in[14];
    const float* cls_w  = (const float*)d_in[15];
    const float* cls_b  = (const float*)d_in[16];
    (void)in_sizes; (void)n_in; (void)out_size; (void)ws_size;

    float* out  = (float*)d_out;          // [32768]
    float* feat = out + 32768;            // [32768][256]

    char* ws = (char*)d_ws;
    unsigned* h_pk   = (unsigned*)(ws + 0);           // 262144 B
    unsigned* c_pk   = (unsigned*)(ws + 262144);      // 262144 B
    unsigned* ctr    = (unsigned*)(ws + 524288);      // 8192 B   (zeroed region ends 532480)
    short*  stagesP  = (short*)  (ws + 532480);       // 32768*96*2    = 6291456
    short*  st1      = (short*)  (ws + 6823936);      // 32768*256*2   = 16777216
    short*  st2      = (short*)  (ws + 23601152);     // 32768*512*2   = 33554432
    short*  w1T      = (short*)  (ws + 57155584);     // 256*96*2      = 49152
    short*  w2T      = (short*)  (ws + 57204736);     // 512*256*2     = 262144
    short*  w3T      = (short*)  (ws + 57466880);     // 1024*512*2    = 1048576
    short*  UwT      = (short*)  (ws + 58515456);     // 1024*2048*2   = 4194304
    short*  xin      = (short*)  (ws + 62709760);     // 32768*2048*2  = 134217728
    float*  u        = (float*)  (ws + 196927488);    // 256*128*1024*4= 134217728

    // zero scan sync/state area (h_pk, c_pk, ctr)
    hipMemsetAsync(d_ws, 0, 532480, stream);

    // conversions
    k_cvt_x<<<8388608 / 256, 256, 0, stream>>>(x, xin);
    k_cvt_stages<<<(32768 * 96) / 256, 256, 0, stream>>>(stages, stagesP);
    k_transpose<<<(256 * 96) / 256, 256, 0, stream>>>(se_w1, w1T, 67, 256, 96);
    k_transpose<<<(512 * 256) / 256, 256, 0, stream>>>(se_w2, w2T, 256, 512, 256);
    k_transpose<<<(1024 * 512) / 256, 256, 0, stream>>>(se_w3, w3T, 512, 1024, 512);
    k_transpose<<<(1024 * 2048) / 256, 256, 0, stream>>>(U_w, UwT, 2048, 1024, 2048);

    // stage MLP (bf16 MFMA, relu, bf16 out)
    k_gemm<<<dim3(2, 256), 256, 0, stream>>>(stagesP, 96, w1T, 96, se_b1, 96, 1 | 2,
                                             nullptr, st1, 256);
    k_gemm<<<dim3(4, 256), 256, 0, stream>>>(st1, 256, w2T, 256, se_b2, 256, 1 | 2,
                                             nullptr, st2, 512);
    // st3 written into xin columns [1024,2048)
    k_gemm<<<dim3(8, 256), 256, 0, stream>>>(st2, 512, w3T, 512, se_b3, 512, 1 | 2,
                                             nullptr, xin + 1024, 2048);
    // u = xin @ U_all_w + U_all_b, stored permuted [s][b][1024] f32
    k_gemm<<<dim3(8, 256), 256, 0, stream>>>(xin, 2048, UwT, 2048, U_b, 2048, 4,
                                             u, nullptr, 1024);

    // sequential TLSTM scan (writes feat)
    k_scan<<<256, 256, 0, stream>>>(W_all, W_allb, W_d, W_d_b, u, tsp,
                                    ctr, h_pk, c_pk, feat);

    // classifier
    k_cls<<<8192, 256, 0, stream>>>(feat, cls_w, cls_b, out);
}

// Round 3
// 1479.196 us; speedup vs baseline: 2.5170x; 2.5170x over previous
//
#include <hip/hip_runtime.h>
#include <hip/hip_bf16.h>
#include <stdint.h>

#define B_ 128
#define S_ 256
#define H_ 256

typedef __attribute__((ext_vector_type(8))) short short8;
typedef __attribute__((ext_vector_type(4))) float f32x4;

__device__ __forceinline__ short f2bf_s(float x){
    union { __hip_bfloat16 b; short s; } u; u.b = __float2bfloat16(x); return u.s;
}
__device__ __forceinline__ float bf2f_s(short s){
    union { __hip_bfloat16 b; short s2; } u; u.s2 = s; return __bfloat162float(u.b);
}
__device__ __forceinline__ void load_lds16(const void* g, void* l){
    __builtin_amdgcn_global_load_lds(
        (const __attribute__((address_space(1))) void*)g,
        (__attribute__((address_space(3))) void*)l, 16, 0, 0);
}
__device__ __forceinline__ float sigmoidf_(float x){
    return 1.0f / (1.0f + __expf(-x));
}

// ---------- conversion kernels ----------

// x [32768][1024] f32 -> xin[:, 0:1024) bf16 (xin row stride 2048)
__global__ void k_cvt_x(const float* __restrict__ x, short* __restrict__ xin){
    int q = blockIdx.x * blockDim.x + threadIdx.x;   // quad index, total 8388608
    if (q >= 8388608) return;
    const float4 v = ((const float4*)x)[q];
    int r = q >> 8;            // row (256 quads per row)
    int c4 = (q & 255) << 2;   // col
    short4 o;
    o.x = f2bf_s(v.x); o.y = f2bf_s(v.y); o.z = f2bf_s(v.z); o.w = f2bf_s(v.w);
    *(short4*)(xin + (int64_t)r * 2048 + c4) = o;
}

// stages [32768][67] f32 -> stagesP [32768][96] bf16 (zero pad)
__global__ void k_cvt_stages(const float* __restrict__ st, short* __restrict__ sp){
    int i = blockIdx.x * blockDim.x + threadIdx.x;   // total 32768*96
    if (i >= 32768 * 96) return;
    int r = i / 96, k = i - r * 96;
    sp[i] = (k < 67) ? f2bf_s(st[(int64_t)r * 67 + k]) : (short)0;
}

// w [K][N] f32 -> wt [N][Kpad] bf16 (zero pad k>=K)
__global__ void k_transpose(const float* __restrict__ w, short* __restrict__ wt,
                            int K, int N, int Kpad){
    int i = blockIdx.x * blockDim.x + threadIdx.x;   // total N*Kpad
    if (i >= N * Kpad) return;
    int n = i / Kpad, k = i - n * Kpad;
    wt[i] = (k < K) ? f2bf_s(w[(int64_t)k * N + n]) : (short)0;
}

// ---------- bf16 MFMA GEMM: C[M,N] = A[M,K] @ BT[N,K]^T + bias ----------
// 128x128 tile, BK=32, 256 threads, global_load_lds width-16 staging (m97 structure)
// flags: 1=relu, 2=store bf16 to Cb, 4=permuted f32 store (u layout [s][b][1024])
__global__ __launch_bounds__(256) void k_gemm(
    const short* __restrict__ A, int lda,
    const short* __restrict__ BT, int ldb,
    const float* __restrict__ bias,
    int K, int flags,
    float* __restrict__ Cf, short* __restrict__ Cb, int ldc)
{
    __shared__ __align__(16) short At[128 * 32];
    __shared__ __align__(16) short Bt[128 * 32];
    const int tid = threadIdx.x;
    const int lane = tid & 63, w = tid >> 6;
    const int q = lane >> 4, m = lane & 15;
    const int wr = w >> 1, wc = w & 1;
    const int bm = blockIdx.y, bn = blockIdx.x;

    const short* Ablk = A + (int64_t)bm * 128 * lda;
    const short* Bblk = BT + (int64_t)bn * 128 * ldb;

    f32x4 acc[4][4] = {};

    for (int k0 = 0; k0 < K; k0 += 32){
#pragma unroll
        for (int call = 0; call < 2; ++call){
            int chunk = (call * 4 + w) * 64 + lane;
            int row = chunk >> 2, co = (chunk & 3) * 8;
            load_lds16(Ablk + (int64_t)row * lda + k0 + co, At + (call * 4 + w) * 512);
            load_lds16(Bblk + (int64_t)row * ldb + k0 + co, Bt + (call * 4 + w) * 512);
        }
        __syncthreads();
        short8 af[4], bfr[4];
#pragma unroll
        for (int mt = 0; mt < 4; ++mt)
            af[mt] = *(const short8*)(At + (wr * 64 + mt * 16 + m) * 32 + q * 8);
#pragma unroll
        for (int nt = 0; nt < 4; ++nt)
            bfr[nt] = *(const short8*)(Bt + (wc * 64 + nt * 16 + m) * 32 + q * 8);
#pragma unroll
        for (int mt = 0; mt < 4; ++mt)
#pragma unroll
            for (int nt = 0; nt < 4; ++nt)
                acc[mt][nt] = __builtin_amdgcn_mfma_f32_16x16x32_bf16(
                    af[mt], bfr[nt], acc[mt][nt], 0, 0, 0);
        __syncthreads();
    }

#pragma unroll
    for (int mt = 0; mt < 4; ++mt){
#pragma unroll
        for (int nt = 0; nt < 4; ++nt){
            int col = bn * 128 + wc * 64 + nt * 16 + m;
            float bv = bias[col];
#pragma unroll
            for (int rg = 0; rg < 4; ++rg){
                int row = bm * 128 + wr * 64 + mt * 16 + q * 4 + rg;
                float v = acc[mt][nt][rg] + bv;
                if (flags & 1) v = fmaxf(v, 0.0f);
                if (flags & 2){
                    Cb[(int64_t)row * ldc + col] = f2bf_s(v);
                } else if (flags & 4){
                    int s = row & 255, b = row >> 8;
                    Cf[((int64_t)s * 128 + b) * 1024 + col] = v;
                } else {
                    Cf[(int64_t)row * ldc + col] = v;
                }
            }
        }
    }
}

// ---------- TLSTM scan ----------
// 256 WGs = 8 row-groups (16 batch rows each) x 32 col-groups (8 cell cols each).
// Weights resident in LDS as bf16 hi/lo B-fragments (bf16x3 ~ f32 precision).
// h/c exchange via s-indexed FRESH buffers h_seq/c_seq[s][128][256] (packed
// bf16 hi|lo u32). Fresh addresses each step => no consumer L2 staleness is
// possible (lines never touched earlier in the dispatch), so:
//   - producer: relaxed agent atomic stores (write-through to LLC, no dirty L2)
//   - consumer: PLAIN cached vector loads (no buffer_inv)
//   - counter: relaxed fetch_add; spin polls with fetch_add(0) (RMW at LLC,
//     always fresh). Zero per-step cache maintenance ops.
// c for the local cell update is carried in a register (owner thread fixed).
__global__ __launch_bounds__(256, 2) void k_scan(
    const float* __restrict__ W_all, const float* __restrict__ W_all_b,
    const float* __restrict__ W_d,   const float* __restrict__ W_d_b,
    const float* __restrict__ u,     const float* __restrict__ tsp,
    unsigned* __restrict__ ctr,      // [8][256]
    unsigned* __restrict__ h_seq,    // [257][128][256] packed bf16 hi|lo
    unsigned* __restrict__ c_seq,    // [257][128][256]
    float* __restrict__ feat)        // [B][S][H]
{
    __shared__ __align__(16) short wf_hi[3][8][64][8];
    __shared__ __align__(16) short wf_lo[3][8][64][8];
    __shared__ float Dg[3][16][17];

    const int tid = threadIdx.x;
    const int r = blockIdx.x >> 5, cg = blockIdx.x & 31;
    const int j0 = cg * 8, row0 = r * 16;

    // one-time: load this WG's weight slice into LDS fragments (hi/lo bf16)
    for (int idx = tid; idx < 3 * 8 * 64; idx += 256){
        int t = idx / 512;
        int kk = (idx >> 6) & 7;
        int ln = idx & 63;
        int qq = ln >> 4, nn = ln & 15;
#pragma unroll
        for (int jj = 0; jj < 8; ++jj){
            int k = kk * 32 + qq * 8 + jj;
            float v = 0.0f;
            if (t < 2){
                int ngl = (nn < 8) ? (t * 512 + j0 + nn) : (t * 512 + 256 + j0 + nn - 8);
                v = W_all[(int64_t)k * 1024 + ngl];
            } else if (nn < 8){
                v = W_d[(int64_t)k * 256 + j0 + nn];
            }
            short hi = f2bf_s(v);
            wf_hi[t][kk][ln][jj] = hi;
            wf_lo[t][kk][ln][jj] = f2bf_s(v - bf2f_s(hi));
        }
    }
    __syncthreads();

    const int lane = tid & 63, w = tid >> 6;
    const int q = lane >> 4, al15 = lane & 15;

    // per-owner-thread registers (tid<128 owns cell (row0 + tid>>3, j0 + (tid&7)))
    const int b_own  = tid >> 3;            // valid for tid<128
    const int jl_own = tid & 7;
    const int gb     = row0 + b_own;
    const int gj     = j0 + jl_own;
    float c_reg = 0.0f;

    // bias values are loop-invariant: hoist
    float bf_ = 0, bi_ = 0, bo_ = 0, bg_ = 0, bd_ = 0;
    if (tid < 128){
        bf_ = W_all_b[gj];
        bi_ = W_all_b[256 + gj];
        bo_ = W_all_b[512 + gj];
        bg_ = W_all_b[768 + gj];
        bd_ = W_d_b[gj];
    }

    for (int s = 0; s < 256; ++s){
        // prefetch u/tsp for this step before the sync (independent of recurrence)
        float uf = 0, ui = 0, uo = 0, ug = 0, tt = 0;
        if (tid < 128){
            const float* urow = u + ((int64_t)s * 128 + gb) * 1024;
            uf = urow[gj];       ui = urow[256 + gj];
            uo = urow[512 + gj]; ug = urow[768 + gj];
            tt = tsp[gb * 256 + s];
        }

        if (s > 0 && tid == 0){
            // RMW poll at LLC: always fresh, no cache ops
            while (__hip_atomic_fetch_add(&ctr[r * 256 + s - 1], 0u,
                                          __ATOMIC_RELAXED, __HIP_MEMORY_SCOPE_AGENT) < 32u)
                ;
        }
        __syncthreads();

        if (w < 3){
            const unsigned* src = (w < 2 ? h_seq : c_seq) + (int64_t)s * 32768
                                  + (row0 + al15) * 256;
            f32x4 acc = {0.0f, 0.0f, 0.0f, 0.0f};
#pragma unroll
            for (int kk = 0; kk < 8; ++kk){
                int kb = kk * 32 + q * 8;
                const uint4* p = (const uint4*)(src + kb);
                uint4 da = p[0], db = p[1];
                unsigned w0 = da.x, w1 = da.y, w2 = da.z, w3 = da.w;
                unsigned w4 = db.x, w5 = db.y, w6 = db.z, w7 = db.w;
                union { short8 v; unsigned u32[4]; } ah, al;
                ah.u32[0] = __builtin_amdgcn_perm(w1, w0, 0x05040100u);
                ah.u32[1] = __builtin_amdgcn_perm(w3, w2, 0x05040100u);
                ah.u32[2] = __builtin_amdgcn_perm(w5, w4, 0x05040100u);
                ah.u32[3] = __builtin_amdgcn_perm(w7, w6, 0x05040100u);
                al.u32[0] = __builtin_amdgcn_perm(w1, w0, 0x07060302u);
                al.u32[1] = __builtin_amdgcn_perm(w3, w2, 0x07060302u);
                al.u32[2] = __builtin_amdgcn_perm(w5, w4, 0x07060302u);
                al.u32[3] = __builtin_amdgcn_perm(w7, w6, 0x07060302u);
                short8 bh = *(const short8*)&wf_hi[w][kk][lane][0];
                short8 bl = *(const short8*)&wf_lo[w][kk][lane][0];
                acc = __builtin_amdgcn_mfma_f32_16x16x32_bf16(ah.v, bh, acc, 0, 0, 0);
                acc = __builtin_amdgcn_mfma_f32_16x16x32_bf16(ah.v, bl, acc, 0, 0, 0);
                acc = __builtin_amdgcn_mfma_f32_16x16x32_bf16(al.v, bh, acc, 0, 0, 0);
            }
#pragma unroll
            for (int rg = 0; rg < 4; ++rg)
                Dg[w][q * 4 + rg][al15] = acc[rg];
        }
        __syncthreads();

        if (tid < 128){
            float fpre = Dg[0][b_own][jl_own]     + uf + bf_;
            float ipre = Dg[0][b_own][8 + jl_own] + ui + bi_;
            float opre = Dg[1][b_own][jl_own]     + uo + bo_;
            float gpre = Dg[1][b_own][8 + jl_own] + ug + bg_;
            float spre = Dg[2][b_own][jl_own]     + bd_;

            float cs1 = tanhf(spre);
            float cadj = (c_reg - cs1) + cs1 * tt;
            float fg = sigmoidf_(fpre);
            float ig = sigmoidf_(ipre);
            float og = sigmoidf_(opre);
            float gg = sigmoidf_(gpre);
            float cn = fg * cadj + ig * gg;
            float hn = og * tanhf(cn);
            c_reg = cn;

            short chi = f2bf_s(cn);
            unsigned cword = (unsigned)(unsigned short)chi |
                             ((unsigned)(unsigned short)f2bf_s(cn - bf2f_s(chi)) << 16);
            short hhi = f2bf_s(hn);
            unsigned hword = (unsigned)(unsigned short)hhi |
                             ((unsigned)(unsigned short)f2bf_s(hn - bf2f_s(hhi)) << 16);
            int64_t oidx = (int64_t)(s + 1) * 32768 + gb * 256 + gj;
            __hip_atomic_store(&c_seq[oidx], cword,
                               __ATOMIC_RELAXED, __HIP_MEMORY_SCOPE_AGENT);
            __hip_atomic_store(&h_seq[oidx], hword,
                               __ATOMIC_RELAXED, __HIP_MEMORY_SCOPE_AGENT);
            __builtin_nontemporal_store(hn, &feat[((int64_t)gb * 256 + s) * 256 + gj]);
        }
        __syncthreads();   // vmcnt(0) drain: all waves' stores at LLC before signal
        if (tid == 0)
            __hip_atomic_fetch_add(&ctr[r * 256 + s], 1u,
                                   __ATOMIC_RELAXED, __HIP_MEMORY_SCOPE_AGENT);
    }
}

// ---------- classifier: out[r] = feat[r,:] . cls_w + cls_b ----------
__global__ __launch_bounds__(256) void k_cls(
    const float* __restrict__ feat, const float* __restrict__ cls_w,
    const float* __restrict__ cls_b, float* __restrict__ out)
{
    int tid = threadIdx.x, lane = tid & 63, w = tid >> 6;
    int row = blockIdx.x * 4 + w;
    float4 v  = ((const float4*)(feat + (int64_t)row * 256))[lane];
    float4 cw = ((const float4*)cls_w)[lane];
    float d = v.x * cw.x + v.y * cw.y + v.z * cw.z + v.w * cw.w;
#pragma unroll
    for (int off = 32; off > 0; off >>= 1)
        d += __shfl_down(d, off, 64);
    if (lane == 0) out[row] = d + cls_b[0];
}

extern "C" void kernel_launch(void* const* d_in, const int* in_sizes, int n_in,
                              void* d_out, int out_size, void* d_ws, size_t ws_size,
                              hipStream_t stream) {
    const float* x      = (const float*)d_in[0];
    const float* stages = (const float*)d_in[1];
    const float* tsp    = (const float*)d_in[2];
    const float* se_w1  = (const float*)d_in[3];
    const float* se_b1  = (const float*)d_in[4];
    const float* se_w2  = (const float*)d_in[5];
    const float* se_b2  = (const float*)d_in[6];
    const float* se_w3  = (const float*)d_in[7];
    const float* se_b3  = (const float*)d_in[8];
    const float* W_all  = (const float*)d_in[9];
    const float* W_allb = (const float*)d_in[10];
    const float* U_w    = (const float*)d_in[11];
    const float* U_b    = (const float*)d_in[12];
    const float* W_d    = (const float*)d_in[13];
    const float* W_d_b  = (const float*)d_in[14];
    const float* cls_w  = (const float*)d_in[15];
    const float* cls_b  = (const float*)d_in[16];
    (void)in_sizes; (void)n_in; (void)out_size; (void)ws_size;

    float* out  = (float*)d_out;          // [32768]
    float* feat = out + 32768;            // [32768][256]

    char* ws = (char*)d_ws;
    unsigned* ctr    = (unsigned*)(ws + 0);           // 8192 B
    short*  stagesP  = (short*)  (ws + 532480);       // 32768*96*2    = 6291456
    short*  st1      = (short*)  (ws + 6823936);      // 32768*256*2   = 16777216
    short*  st2      = (short*)  (ws + 23601152);     // 32768*512*2   = 33554432
    short*  w1T      = (short*)  (ws + 57155584);     // 256*96*2      = 49152
    short*  w2T      = (short*)  (ws + 57204736);     // 512*256*2     = 262144
    short*  w3T      = (short*)  (ws + 57466880);     // 1024*512*2    = 1048576
    short*  UwT      = (short*)  (ws + 58515456);     // 1024*2048*2   = 4194304
    short*  xin      = (short*)  (ws + 62709760);     // 32768*2048*2  = 134217728
    float*  u        = (float*)  (ws + 196927488);    // 256*128*1024*4= 134217728
    // h_seq/c_seq OVERLAP the xin region: xin is dead once the U-projection
    // GEMM has run, and the scan (stream-ordered after it) is the only user.
    // 2 x 257*128*256*4 B = 2 x 33,685,504 B = 67.4 MB < 134 MB (xin size).
    unsigned* h_seq  = (unsigned*)(ws + 62709760);
    unsigned* c_seq  = (unsigned*)(ws + 62709760 + 33685504);

    // zero the sync counters and the s=0 slices of h_seq/c_seq.
    // NOTE: these memsets run BEFORE the gemms that write xin; h_seq[0]/c_seq[0]
    // occupy xin bytes [0,131072) and [33685504,33816576) which hold A-tile
    // rows for the U-GEMM — so zero them AFTER the U-GEMM instead (see below).
    hipMemsetAsync(ctr, 0, 8192, stream);

    // conversions
    k_cvt_x<<<8388608 / 256, 256, 0, stream>>>(x, xin);
    k_cvt_stages<<<(32768 * 96) / 256, 256, 0, stream>>>(stages, stagesP);
    k_transpose<<<(256 * 96) / 256, 256, 0, stream>>>(se_w1, w1T, 67, 256, 96);
    k_transpose<<<(512 * 256) / 256, 256, 0, stream>>>(se_w2, w2T, 256, 512, 256);
    k_transpose<<<(1024 * 512) / 256, 256, 0, stream>>>(se_w3, w3T, 512, 1024, 512);
    k_transpose<<<(1024 * 2048) / 256, 256, 0, stream>>>(U_w, UwT, 2048, 1024, 2048);

    // stage MLP (bf16 MFMA, relu, bf16 out)
    k_gemm<<<dim3(2, 256), 256, 0, stream>>>(stagesP, 96, w1T, 96, se_b1, 96, 1 | 2,
                                             nullptr, st1, 256);
    k_gemm<<<dim3(4, 256), 256, 0, stream>>>(st1, 256, w2T, 256, se_b2, 256, 1 | 2,
                                             nullptr, st2, 512);
    // st3 written into xin columns [1024,2048)
    k_gemm<<<dim3(8, 256), 256, 0, stream>>>(st2, 512, w3T, 512, se_b3, 512, 1 | 2,
                                             nullptr, xin + 1024, 2048);
    // u = xin @ U_all_w + U_all_b, stored permuted [s][b][1024] f32
    k_gemm<<<dim3(8, 256), 256, 0, stream>>>(xin, 2048, UwT, 2048, U_b, 2048, 4,
                                             u, nullptr, 1024);

    // xin is now dead: zero the s=0 state slices (stream-ordered after U-GEMM)
    hipMemsetAsync(h_seq, 0, 131072, stream);
    hipMemsetAsync(c_seq, 0, 131072, stream);

    // sequential TLSTM scan (writes feat)
    k_scan<<<256, 256, 0, stream>>>(W_all, W_allb, W_d, W_d_b, u, tsp,
                                    ctr, h_seq, c_seq, feat);

    // classifier
    k_cls<<<8192, 256, 0, stream>>>(feat, cls_w, cls_b, out);
}